// Round 12
// baseline (178.597 us; speedup 1.0000x reference)
//
#include <hip/hip_runtime.h>
#include <stdint.h>

// ---------- types ----------
typedef __attribute__((ext_vector_type(8))) short s8v;   // 8 bf16 (4 VGPRs)
typedef __attribute__((ext_vector_type(4))) float f4v;   // MFMA accumulator

// ---------- helpers ----------
__device__ __forceinline__ unsigned short f2bf(float f) {
  unsigned u = __float_as_uint(f);
  u = u + 0x7FFFu + ((u >> 16) & 1u);   // RNE
  return (unsigned short)(u >> 16);
}
// monotone float->uint map: order(enc(a)) == order(a); 0 is below enc of any real float.
__device__ __forceinline__ unsigned encf(float f) {
  unsigned i = __float_as_uint(f);
  return (i & 0x80000000u) ? ~i : (i | 0x80000000u);
}
__device__ __forceinline__ float decf(unsigned u) {
  unsigned i = (u & 0x80000000u) ? (u & 0x7FFFFFFFu) : ~u;
  return __uint_as_float(i);
}
__device__ __forceinline__ void gload_lds16(const unsigned short* g, unsigned short* l) {
  __builtin_amdgcn_global_load_lds((const __attribute__((address_space(1))) void*)g,
                                   (__attribute__((address_space(3))) void*)l, 16, 0, 0);
}

// ---------- fused: q,a fp32->bf16; U -> Ut bf16 transposed; zero rmax/cmax ----------
__global__ void convert_kernel(const float4* __restrict__ q, const float4* __restrict__ a,
                               const float* __restrict__ U,
                               ushort4* __restrict__ qb, ushort4* __restrict__ ab,
                               unsigned short* __restrict__ Ut,
                               unsigned* __restrict__ rcmax) {
  const int bx = blockIdx.x;
  if (bx < 8192) {
    const int i = bx * 256 + threadIdx.x;
    float4 v = q[i];
    qb[i] = make_ushort4(f2bf(v.x), f2bf(v.y), f2bf(v.z), f2bf(v.w));
    float4 w = a[i];
    ab[i] = make_ushort4(f2bf(w.x), f2bf(w.y), f2bf(w.z), f2bf(w.w));
  } else if (bx < 8256) {
    // U transpose: 64 blocks x 256 thr, 4 elements each (tiny: 256 KB read)
    const int idx = (bx - 8192) * 256 + threadIdx.x;   // 0..16383
    const int n  = idx >> 6;
    const int k4 = (idx & 63) * 4;
    ushort4 o;
    o.x = f2bf(U[(k4 + 0) * 256 + n]);
    o.y = f2bf(U[(k4 + 1) * 256 + n]);
    o.z = f2bf(U[(k4 + 2) * 256 + n]);
    o.w = f2bf(U[(k4 + 3) * 256 + n]);
    *(ushort4*)&Ut[n * 256 + k4] = o;
  } else {
    // zero rmax+cmax (64K uints): 64 blocks x 256 thr x 4
    const int idx = (bx - 8256) * 256 + threadIdx.x;   // 0..16383
    *(uint4*)&rcmax[idx * 4] = make_uint4(0u, 0u, 0u, 0u);
  }
}

// ---------- GEMM C[m,n] = sum_k A[m,k]*B[n,k]  (row-major, K=256, ld=256) ----------
// 128x128 tile, 4 waves (2x2), 256 threads. NO __launch_bounds__: R7/R11 show
// the allocator gives VGPR 64 / SGPR 32 on its own; bare (256) -> VGPR 80 [R9],
// (256,4) -> SGPR 112, +6 us [R10]. (Bounds needed only if acc grows: R8 spill.)
// LDS XOR-swizzled: element (row, 16B-chunk c) lives at chunk c ^ (row&7);
// staging permutes the GLOBAL source chunk (inverse; issue base rows mult of 8).
// MODE 0: store C bf16. MODE 1: row/col maxes -> encoded-uint global atomics;
//   grid (b, tn, tm) => XCD(~linear%8) == b%8 pins each batch to one XCD L2;
//   (tn==0,tm==0) blocks also zero `out` (runs before wsum in stream order).
template<int MODE>
__global__ void gemm_bt(const unsigned short* __restrict__ A,
                        const unsigned short* __restrict__ Bm,
                        long strideA, long strideB,
                        unsigned short* __restrict__ C,
                        unsigned* __restrict__ rowmax,
                        unsigned* __restrict__ colmax,
                        float* __restrict__ outz) {
  constexpr int AROWS = 128;
  constexpr int BROWS = 128;
  constexpr int RPI = 32;                // rows staged per issue (256 thr * 16B / 128B)

  __shared__ unsigned short As[AROWS * 64];
  __shared__ unsigned short Bs[BROWS * 64];
  __shared__ unsigned rowLds[AROWS];
  __shared__ unsigned colLds[BROWS];

  const int tid = threadIdx.x;
  int tm, tn, b;
  if (MODE == 1) { b = blockIdx.x; tn = blockIdx.y; tm = blockIdx.z; }
  else           { tm = blockIdx.x; tn = blockIdx.y; b = blockIdx.z; }
  const unsigned short* Ab = A + (long)b * strideA + (long)tm * AROWS * 256;
  const unsigned short* Bb = Bm + (long)b * strideB + (long)tn * BROWS * 256;

  const int lane = tid & 63;
  const int m16  = lane & 15;
  const int quad = lane >> 4;
  const int wave = tid >> 6;
  const int wm   = wave >> 1, wn = wave & 1;
  const int srow = tid >> 3;                                // staging row within issue
  const int scol = (((tid & 7) ^ (srow & 7))) * 8;          // swizzled global source chunk

  if (MODE == 1) {
    if (tid < AROWS) rowLds[tid] = 0u;
    if (tid < BROWS) colLds[tid] = 0u;
    if (tn == 0 && tm == 0) {                // zero out for this batch (before wsum)
      outz[b * 256 + tid] = 0.f;
      outz[4096 + b * 256 + tid] = 0.f;
    }
  }

  f4v acc[4][4] = {};

  for (int kt = 0; kt < 4; ++kt) {
    const int k0 = kt * 64;
    __syncthreads();                  // LDS free from previous iter
    #pragma unroll
    for (int i = 0; i < AROWS / RPI; ++i) {
      const int r = i * RPI + srow;
      gload_lds16(Ab + (long)r * 256 + k0 + scol, &As[i * RPI * 64 + tid * 8]);
    }
    #pragma unroll
    for (int i = 0; i < BROWS / RPI; ++i) {
      const int r = i * RPI + srow;
      gload_lds16(Bb + (long)r * 256 + k0 + scol, &Bs[i * RPI * 64 + tid * 8]);
    }
    __syncthreads();                  // staging complete
    #pragma unroll
    for (int kk = 0; kk < 2; ++kk) {
      const int cs = ((kk * 4 + quad) ^ (m16 & 7)) * 8;   // read swizzle (row&7 == m16&7)
      s8v af[4], bfv[4];
      #pragma unroll
      for (int i = 0; i < 4; ++i)
        af[i] = *(const s8v*)&As[(wm * 64 + i * 16 + m16) * 64 + cs];
      #pragma unroll
      for (int j = 0; j < 4; ++j)
        bfv[j] = *(const s8v*)&Bs[(wn * 64 + j * 16 + m16) * 64 + cs];
      #pragma unroll
      for (int i = 0; i < 4; ++i)
        #pragma unroll
        for (int j = 0; j < 4; ++j)
          acc[i][j] = __builtin_amdgcn_mfma_f32_16x16x32_bf16(af[i], bfv[j], acc[i][j], 0, 0, 0);
    }
  }

  if (MODE == 0) {
    // C/D layout: col = lane&15, row = quad*4 + reg  (verified mapping)
    #pragma unroll
    for (int i = 0; i < 4; ++i)
      #pragma unroll
      for (int r = 0; r < 4; ++r) {
        const long row = (long)tm * AROWS + wm * 64 + i * 16 + quad * 4 + r;
        #pragma unroll
        for (int j = 0; j < 4; ++j) {
          const int col = tn * BROWS + wn * 64 + j * 16 + m16;
          C[row * 256 + col] = f2bf(acc[i][j][r]);
        }
      }
  } else {
    // ---- row maxes ----
    #pragma unroll
    for (int i = 0; i < 4; ++i)
      #pragma unroll
      for (int r = 0; r < 4; ++r) {
        float v = fmaxf(fmaxf(acc[i][0][r], acc[i][1][r]), fmaxf(acc[i][2][r], acc[i][3][r]));
        #pragma unroll
        for (int d2 = 1; d2 < 16; d2 <<= 1) v = fmaxf(v, __shfl_xor(v, d2));
        if (m16 == 0) atomicMax(&rowLds[wm * 64 + i * 16 + quad * 4 + r], encf(v));
      }
    // ---- col maxes ----
    #pragma unroll
    for (int j = 0; j < 4; ++j) {
      float v = -3.4e38f;
      #pragma unroll
      for (int i = 0; i < 4; ++i)
        #pragma unroll
        for (int r = 0; r < 4; ++r) v = fmaxf(v, acc[i][j][r]);
      v = fmaxf(v, __shfl_xor(v, 16));
      v = fmaxf(v, __shfl_xor(v, 32));
      if (quad == 0) atomicMax(&colLds[wn * 64 + j * 16 + m16], encf(v));
    }
    __syncthreads();
    if (tid < AROWS) {
      atomicMax(&rowmax[(long)b * 2048 + tm * AROWS + tid], rowLds[tid]);
    } else if (tid < AROWS + BROWS) {
      atomicMax(&colmax[(long)b * 2048 + tn * BROWS + (tid - AROWS)], colLds[tid - AROWS]);
    }
  }
}

// ---------- fused softmax + weighted sum (bf16 inputs, 16B/lane loads) ----------
// block (chunk 0..15, b 0..15, z 0..1); re-derives softmax stats (cheap) then
// pools 128 rows. Lane covers d = (tid&31)*8..+7 via uint4 (8 bf16); row-group
// tid>>5 strides 8 rows. fp32 accumulate, LDS tree-reduce, atomicAdd to out.
__global__ void wsum_kernel(const uint4* __restrict__ qb, const uint4* __restrict__ ab,
                            const unsigned* __restrict__ rowmax, const unsigned* __restrict__ colmax,
                            float* __restrict__ out) {
  const int tid = threadIdx.x;
  const int chunk = blockIdx.x;
  const int b = blockIdx.y;
  const int z = blockIdx.z;
  const unsigned* e = z ? colmax : rowmax;
  const uint4* src = z ? ab : qb;

  __shared__ float sm[4];
  __shared__ float ss[4];
  __shared__ float wLds[128];
  __shared__ float red[256 * 8];   // 8 KB

  // softmax stats over all 2048 positions of batch b
  float x[8];
  float m = -3.4e38f;
  #pragma unroll
  for (int j = 0; j < 8; ++j) {
    x[j] = tanhf(decf(e[b * 2048 + j * 256 + tid]));
    m = fmaxf(m, x[j]);
  }
  #pragma unroll
  for (int d2 = 1; d2 < 64; d2 <<= 1) m = fmaxf(m, __shfl_xor(m, d2));
  if ((tid & 63) == 0) sm[tid >> 6] = m;
  __syncthreads();
  m = fmaxf(fmaxf(sm[0], sm[1]), fmaxf(sm[2], sm[3]));
  float s = 0.f;
  #pragma unroll
  for (int j = 0; j < 8; ++j) s += expf(x[j] - m);
  #pragma unroll
  for (int d2 = 1; d2 < 64; d2 <<= 1) s += __shfl_xor(s, d2);
  if ((tid & 63) == 0) ss[tid >> 6] = s;
  __syncthreads();
  const float inv = 1.f / (ss[0] + ss[1] + ss[2] + ss[3]);

  // weights for this chunk's 128 rows
  if (tid < 128) {
    float xv = tanhf(decf(e[b * 2048 + chunk * 128 + tid]));
    wLds[tid] = expf(xv - m) * inv;
  }
  __syncthreads();

  // 16B/lane: row = 32 uint4; lane dg covers d = dg*8..dg*8+7
  const int dg = tid & 31;
  const int rg = tid >> 5;       // 0..7, rows stride 8
  float acc[8] = {};
  const long rowbase = (long)b * 2048 + chunk * 128;
  for (int t = rg; t < 128; t += 8) {
    const float wgt = wLds[t];
    uint4 v = src[(rowbase + t) * 32 + dg];
    acc[0] += wgt * __uint_as_float(v.x << 16);
    acc[1] += wgt * __uint_as_float(v.x & 0xFFFF0000u);
    acc[2] += wgt * __uint_as_float(v.y << 16);
    acc[3] += wgt * __uint_as_float(v.y & 0xFFFF0000u);
    acc[4] += wgt * __uint_as_float(v.z << 16);
    acc[5] += wgt * __uint_as_float(v.z & 0xFFFF0000u);
    acc[6] += wgt * __uint_as_float(v.w << 16);
    acc[7] += wgt * __uint_as_float(v.w & 0xFFFF0000u);
  }
  #pragma unroll
  for (int k = 0; k < 8; ++k) red[tid * 8 + k] = acc[k];
  __syncthreads();
  if (tid < 32) {
    #pragma unroll
    for (int k = 0; k < 8; ++k) {
      float v = 0.f;
      #pragma unroll
      for (int g = 0; g < 8; ++g) v += red[((g << 5) | tid) * 8 + k];
      atomicAdd(&out[z * 4096 + b * 256 + tid * 8 + k], v);
    }
  }
}

// ---------- launch ----------
extern "C" void kernel_launch(void* const* d_in, const int* in_sizes, int n_in,
                              void* d_out, int out_size, void* d_ws, size_t ws_size,
                              hipStream_t stream) {
  const float* q = (const float*)d_in[0];
  const float* a = (const float*)d_in[1];
  const float* U = (const float*)d_in[2];
  float* out = (float*)d_out;

  char* w = (char*)d_ws;
  unsigned short* qb = (unsigned short*)w;
  unsigned short* ab = (unsigned short*)(w + (16ull << 20));
  unsigned short* qU = (unsigned short*)(w + (32ull << 20));
  unsigned short* Ut = (unsigned short*)(w + (48ull << 20));
  unsigned* rmax = (unsigned*)(w + (48ull << 20) + (128ull << 10));
  unsigned* cmax = rmax + 32768;

  // fused q/a bf16-cast + U transpose + rmax/cmax zero (no memset nodes)
  convert_kernel<<<8192 + 64 + 64, 256, 0, stream>>>((const float4*)q, (const float4*)a, U,
                                                     (ushort4*)qb, (ushort4*)ab, Ut, rmax);

  // qU[m,n] = sum_k q[m,k]*Ut[n,k]; M=32768 tiles of 128, N=256 tiles of 128
  gemm_bt<0><<<dim3(256, 2, 1), 256, 0, stream>>>(qb, Ut, 0, 0, qU,
                                                  nullptr, nullptr, nullptr);

  // S row/col maxes per batch (2048x2048), 128x128 tiles; grid (b, tn, tm);
  // also zeroes `out` via (tn==0,tm==0) blocks
  gemm_bt<1><<<dim3(16, 16, 16), 256, 0, stream>>>(qU, ab, 2048 * 256, 2048 * 256,
                                                   nullptr, rmax, cmax, out);

  // fused softmax + weighted pooling (bf16, 16B/lane)
  wsum_kernel<<<dim3(16, 16, 2), 256, 0, stream>>>((const uint4*)qb, (const uint4*)ab,
                                                   rmax, cmax, out);
}

// Round 13
// 171.898 us; speedup vs baseline: 1.0390x; 1.0390x over previous
//
#include <hip/hip_runtime.h>
#include <stdint.h>

// ---------- types ----------
typedef __attribute__((ext_vector_type(8))) short s8v;   // 8 bf16 (4 VGPRs)
typedef __attribute__((ext_vector_type(4))) float f4v;   // MFMA accumulator

// ---------- helpers ----------
__device__ __forceinline__ unsigned short f2bf(float f) {
  unsigned u = __float_as_uint(f);
  u = u + 0x7FFFu + ((u >> 16) & 1u);   // RNE
  return (unsigned short)(u >> 16);
}
// monotone float->uint map: order(enc(a)) == order(a); 0 is below enc of any real float.
__device__ __forceinline__ unsigned encf(float f) {
  unsigned i = __float_as_uint(f);
  return (i & 0x80000000u) ? ~i : (i | 0x80000000u);
}
__device__ __forceinline__ float decf(unsigned u) {
  unsigned i = (u & 0x80000000u) ? (u & 0x7FFFFFFFu) : ~u;
  return __uint_as_float(i);
}
__device__ __forceinline__ void gload_lds16(const unsigned short* g, unsigned short* l) {
  __builtin_amdgcn_global_load_lds((const __attribute__((address_space(1))) void*)g,
                                   (__attribute__((address_space(3))) void*)l, 16, 0, 0);
}

// ---------- fused: q,a fp32->bf16; U -> Ut bf16 transposed; zero rmax/cmax + out ----------
__global__ void convert_kernel(const float4* __restrict__ q, const float4* __restrict__ a,
                               const float* __restrict__ U,
                               ushort4* __restrict__ qb, ushort4* __restrict__ ab,
                               unsigned short* __restrict__ Ut,
                               unsigned* __restrict__ rcmax, float* __restrict__ out) {
  const int bx = blockIdx.x;
  if (bx < 8192) {
    const int i = bx * 256 + threadIdx.x;
    float4 v = q[i];
    qb[i] = make_ushort4(f2bf(v.x), f2bf(v.y), f2bf(v.z), f2bf(v.w));
    float4 w = a[i];
    ab[i] = make_ushort4(f2bf(w.x), f2bf(w.y), f2bf(w.z), f2bf(w.w));
  } else if (bx < 8256) {
    // U transpose: 64 blocks x 256 thr, 4 elements each (tiny: 256 KB read)
    const int idx = (bx - 8192) * 256 + threadIdx.x;   // 0..16383
    const int n  = idx >> 6;
    const int k4 = (idx & 63) * 4;
    ushort4 o;
    o.x = f2bf(U[(k4 + 0) * 256 + n]);
    o.y = f2bf(U[(k4 + 1) * 256 + n]);
    o.z = f2bf(U[(k4 + 2) * 256 + n]);
    o.w = f2bf(U[(k4 + 3) * 256 + n]);
    *(ushort4*)&Ut[n * 256 + k4] = o;
  } else if (bx < 8320) {
    // zero rmax+cmax (64K uints): 64 blocks x 256 thr x 4
    const int idx = (bx - 8256) * 256 + threadIdx.x;   // 0..16383
    *(uint4*)&rcmax[idx * 4] = make_uint4(0u, 0u, 0u, 0u);
  } else {
    // zero out (8192 floats): 32 blocks (stream-ordered before wsum's atomics)
    out[(bx - 8320) * 256 + threadIdx.x] = 0.f;
  }
}

// ---------- fused qU-GEMM + S-max: one block per (batch, 128-row slab) ----------
// Phase 1: qU_tile[128][256] = qb_tile @ Ut, two 128x128 passes, result kept in
//   LDS (XOR-swizzled row-major, 16B chunk c stored at c ^ (row&7)).
// Phase 2: loop 16 a-tiles; stage full 128x256 a-tile (64 KB) via global_load_lds
//   (same swizzle), 8x 32-K MFMA steps vs resident qU tile.
//   Row maxes: block owns rows -> per-lane running max, one shuffle at end, plain
//   store (no global atomics). Col maxes: LDS atomicMax -> one global pass.
// Grid (b, tm): linear%8 == b%8 pins each batch to one XCD L2.
// Dynamic LDS 139776 B (1 block/CU); __launch_bounds__(256,2) = 256 regs/wave
// (acc 64 AGPR + rmx 16 + frags; prevents R8-style spill; no occupancy cost).
__global__ __launch_bounds__(256, 2)
void fused_qu_smax(const unsigned short* __restrict__ qb,
                   const unsigned short* __restrict__ Ut,
                   const unsigned short* __restrict__ ab,
                   unsigned* __restrict__ rowmax,
                   unsigned* __restrict__ colmax) {
  extern __shared__ char smem[];
  unsigned short* qUs   = (unsigned short*)smem;             // 64 KB: qU tile
  unsigned short* Bs2   = (unsigned short*)(smem + 65536);   // 64 KB: a-tile / p1 staging
  unsigned*       colLds = (unsigned*)(smem + 131072);       // 8 KB
  unsigned*       rowLds = (unsigned*)(smem + 139264);       // 512 B

  const int tid = threadIdx.x;
  const int b = blockIdx.x, tm = blockIdx.y;

  const int lane = tid & 63;
  const int m16  = lane & 15;
  const int quad = lane >> 4;
  const int wave = tid >> 6;
  const int wm   = wave >> 1, wn = wave & 1;
  const int srow = tid >> 3;                                // staging row (32/issue)
  const int scol = (((tid & 7) ^ (srow & 7))) * 8;          // swizzled source chunk

  #pragma unroll
  for (int i = 0; i < 8; ++i) colLds[i * 256 + tid] = 0u;
  if (tid < 128) rowLds[tid] = 0u;

  // ================= phase 1: qU tile -> LDS =================
  const unsigned short* Aq = qb + ((long)b * 2048 + tm * 128) * 256;
  unsigned short* S1 = Bs2;            // 16 KB (8192 elems)
  unsigned short* S2 = Bs2 + 8192;     // 16 KB
  #pragma unroll 1
  for (int nh = 0; nh < 2; ++nh) {
    f4v acc[4][4] = {};
    const unsigned short* Bu = Ut + nh * 128 * 256;
    for (int kt = 0; kt < 4; ++kt) {
      const int k0 = kt * 64;
      __syncthreads();                 // staging region free
      #pragma unroll
      for (int i = 0; i < 4; ++i)
        gload_lds16(Aq + (long)(i * 32 + srow) * 256 + k0 + scol, &S1[i * 2048 + tid * 8]);
      #pragma unroll
      for (int i = 0; i < 4; ++i)
        gload_lds16(Bu + (long)(i * 32 + srow) * 256 + k0 + scol, &S2[i * 2048 + tid * 8]);
      __syncthreads();                 // staging complete
      #pragma unroll
      for (int kk = 0; kk < 2; ++kk) {
        const int cs = ((kk * 4 + quad) ^ (m16 & 7)) * 8;
        s8v af[4], bfv[4];
        #pragma unroll
        for (int i = 0; i < 4; ++i)
          af[i] = *(const s8v*)&S1[(wm * 64 + i * 16 + m16) * 64 + cs];
        #pragma unroll
        for (int j = 0; j < 4; ++j)
          bfv[j] = *(const s8v*)&S2[(wn * 64 + j * 16 + m16) * 64 + cs];
        #pragma unroll
        for (int i = 0; i < 4; ++i)
          #pragma unroll
          for (int j = 0; j < 4; ++j)
            acc[i][j] = __builtin_amdgcn_mfma_f32_16x16x32_bf16(af[i], bfv[j], acc[i][j], 0, 0, 0);
      }
    }
    // write acc -> qUs (row-major 256 cols, swizzled 16B chunks)
    // C/D layout: col = lane&15, row = quad*4 + reg (verified mapping)
    #pragma unroll
    for (int i = 0; i < 4; ++i)
      #pragma unroll
      for (int r = 0; r < 4; ++r) {
        const int lr = wm * 64 + i * 16 + quad * 4 + r;
        #pragma unroll
        for (int j = 0; j < 4; ++j) {
          const int col = nh * 128 + wn * 64 + j * 16 + m16;
          const int ch = (col >> 3) ^ (lr & 7);
          qUs[lr * 256 + ch * 8 + (col & 7)] = f2bf(acc[i][j][r]);
        }
      }
  }
  __syncthreads();   // qUs complete; Bs2 free for phase 2

  // ================= phase 2: 16 a-tiles vs resident qU =================
  const unsigned short* Ab_ = ab + (long)b * 2048 * 256;
  float rmx[4][4];
  #pragma unroll
  for (int i = 0; i < 4; ++i)
    #pragma unroll
    for (int r = 0; r < 4; ++r) rmx[i][r] = -3.4e38f;

  #pragma unroll 1
  for (int tb = 0; tb < 16; ++tb) {
    // stage full 128x256 a-tile (64 KB), swizzled
    #pragma unroll
    for (int e = 0; e < 16; ++e) {
      const int u = e * 256 + tid;          // 16B unit: row = u>>5, chunk = u&31
      const int row = u >> 5;
      const int chs = (u & 31) ^ (row & 7);
      gload_lds16(Ab_ + (long)(tb * 128 + row) * 256 + chs * 8, &Bs2[u * 8]);
    }
    __syncthreads();                        // staging complete
    f4v acc[4][4] = {};
    #pragma unroll
    for (int kq = 0; kq < 8; ++kq) {
      const int cs = ((kq * 4 + quad) ^ (m16 & 7)) * 8;
      s8v af[4], bfv[4];
      #pragma unroll
      for (int i = 0; i < 4; ++i)
        af[i] = *(const s8v*)&qUs[(wm * 64 + i * 16 + m16) * 256 + cs];
      #pragma unroll
      for (int j = 0; j < 4; ++j)
        bfv[j] = *(const s8v*)&Bs2[(wn * 64 + j * 16 + m16) * 256 + cs];
      #pragma unroll
      for (int i = 0; i < 4; ++i)
        #pragma unroll
        for (int j = 0; j < 4; ++j)
          acc[i][j] = __builtin_amdgcn_mfma_f32_16x16x32_bf16(af[i], bfv[j], acc[i][j], 0, 0, 0);
    }
    // per-tile reductions: rows -> running per-lane max; cols -> LDS atomicMax
    #pragma unroll
    for (int i = 0; i < 4; ++i)
      #pragma unroll
      for (int r = 0; r < 4; ++r) {
        float v = fmaxf(fmaxf(acc[i][0][r], acc[i][1][r]), fmaxf(acc[i][2][r], acc[i][3][r]));
        rmx[i][r] = fmaxf(rmx[i][r], v);
      }
    #pragma unroll
    for (int j = 0; j < 4; ++j) {
      float v = -3.4e38f;
      #pragma unroll
      for (int i = 0; i < 4; ++i)
        #pragma unroll
        for (int r = 0; r < 4; ++r) v = fmaxf(v, acc[i][j][r]);
      v = fmaxf(v, __shfl_xor(v, 16));
      v = fmaxf(v, __shfl_xor(v, 32));
      if (quad == 0) atomicMax(&colLds[tb * 128 + wn * 64 + j * 16 + m16], encf(v));
    }
    __syncthreads();                        // compute done -> Bs2 restage-safe
  }

  // ---- final row maxes: shuffle over m16, combine wn-waves via LDS, store ----
  #pragma unroll
  for (int i = 0; i < 4; ++i)
    #pragma unroll
    for (int r = 0; r < 4; ++r) {
      float v = rmx[i][r];
      #pragma unroll
      for (int d2 = 1; d2 < 16; d2 <<= 1) v = fmaxf(v, __shfl_xor(v, d2));
      if (m16 == 0) atomicMax(&rowLds[wm * 64 + i * 16 + quad * 4 + r], encf(v));
    }
  __syncthreads();
  if (tid < 128)
    rowmax[(long)b * 2048 + tm * 128 + tid] = rowLds[tid];   // plain store (block owns rows)
  // ---- col maxes: one global atomic pass ----
  #pragma unroll
  for (int i = 0; i < 8; ++i)
    atomicMax(&colmax[(long)b * 2048 + i * 256 + tid], colLds[i * 256 + tid]);
}

// ---------- fused softmax + weighted sum (bf16 inputs, 16B/lane loads) ----------
__global__ void wsum_kernel(const uint4* __restrict__ qb, const uint4* __restrict__ ab,
                            const unsigned* __restrict__ rowmax, const unsigned* __restrict__ colmax,
                            float* __restrict__ out) {
  const int tid = threadIdx.x;
  const int chunk = blockIdx.x;
  const int b = blockIdx.y;
  const int z = blockIdx.z;
  const unsigned* e = z ? colmax : rowmax;
  const uint4* src = z ? ab : qb;

  __shared__ float sm[4];
  __shared__ float ss[4];
  __shared__ float wLds[128];
  __shared__ float red[256 * 8];   // 8 KB

  float x[8];
  float m = -3.4e38f;
  #pragma unroll
  for (int j = 0; j < 8; ++j) {
    x[j] = tanhf(decf(e[b * 2048 + j * 256 + tid]));
    m = fmaxf(m, x[j]);
  }
  #pragma unroll
  for (int d2 = 1; d2 < 64; d2 <<= 1) m = fmaxf(m, __shfl_xor(m, d2));
  if ((tid & 63) == 0) sm[tid >> 6] = m;
  __syncthreads();
  m = fmaxf(fmaxf(sm[0], sm[1]), fmaxf(sm[2], sm[3]));
  float s = 0.f;
  #pragma unroll
  for (int j = 0; j < 8; ++j) s += expf(x[j] - m);
  #pragma unroll
  for (int d2 = 1; d2 < 64; d2 <<= 1) s += __shfl_xor(s, d2);
  if ((tid & 63) == 0) ss[tid >> 6] = s;
  __syncthreads();
  const float inv = 1.f / (ss[0] + ss[1] + ss[2] + ss[3]);

  if (tid < 128) {
    float xv = tanhf(decf(e[b * 2048 + chunk * 128 + tid]));
    wLds[tid] = expf(xv - m) * inv;
  }
  __syncthreads();

  const int dg = tid & 31;
  const int rg = tid >> 5;       // 0..7, rows stride 8
  float acc[8] = {};
  const long rowbase = (long)b * 2048 + chunk * 128;
  for (int t = rg; t < 128; t += 8) {
    const float wgt = wLds[t];
    uint4 v = src[(rowbase + t) * 32 + dg];
    acc[0] += wgt * __uint_as_float(v.x << 16);
    acc[1] += wgt * __uint_as_float(v.x & 0xFFFF0000u);
    acc[2] += wgt * __uint_as_float(v.y << 16);
    acc[3] += wgt * __uint_as_float(v.y & 0xFFFF0000u);
    acc[4] += wgt * __uint_as_float(v.z << 16);
    acc[5] += wgt * __uint_as_float(v.z & 0xFFFF0000u);
    acc[6] += wgt * __uint_as_float(v.w << 16);
    acc[7] += wgt * __uint_as_float(v.w & 0xFFFF0000u);
  }
  #pragma unroll
  for (int k = 0; k < 8; ++k) red[tid * 8 + k] = acc[k];
  __syncthreads();
  if (tid < 32) {
    #pragma unroll
    for (int k = 0; k < 8; ++k) {
      float v = 0.f;
      #pragma unroll
      for (int g = 0; g < 8; ++g) v += red[((g << 5) | tid) * 8 + k];
      atomicAdd(&out[z * 4096 + b * 256 + tid * 8 + k], v);
    }
  }
}

// ---------- launch ----------
extern "C" void kernel_launch(void* const* d_in, const int* in_sizes, int n_in,
                              void* d_out, int out_size, void* d_ws, size_t ws_size,
                              hipStream_t stream) {
  const float* q = (const float*)d_in[0];
  const float* a = (const float*)d_in[1];
  const float* U = (const float*)d_in[2];
  float* out = (float*)d_out;

  char* w = (char*)d_ws;
  unsigned short* qb = (unsigned short*)w;                       // 16 MB
  unsigned short* ab = (unsigned short*)(w + (16ull << 20));     // 16 MB
  unsigned short* Ut = (unsigned short*)(w + (32ull << 20));     // 128 KB
  unsigned* rmax = (unsigned*)(w + (32ull << 20) + (128ull << 10));
  unsigned* cmax = rmax + 32768;

  // allow 139776 B dynamic LDS for the fused kernel (host-side, idempotent)
  constexpr int SMEM = 139776;
  hipFuncSetAttribute((const void*)fused_qu_smax,
                      hipFuncAttributeMaxDynamicSharedMemorySize, SMEM);

  // fused q/a bf16-cast + U transpose + rmax/cmax zero + out zero
  convert_kernel<<<8352, 256, 0, stream>>>((const float4*)q, (const float4*)a, U,
                                           (ushort4*)qb, (ushort4*)ab, Ut, rmax, out);

  // qU tile in LDS + S row/col maxes; grid (b, tm) -> XCD == b%8
  fused_qu_smax<<<dim3(16, 16), 256, SMEM, stream>>>(qb, Ut, ab, rmax, cmax);

  // fused softmax + weighted pooling (bf16, 16B/lane)
  wsum_kernel<<<dim3(16, 16, 2), 256, 0, stream>>>((const uint4*)qb, (const uint4*)ab,
                                                   rmax, cmax, out);
}

// Round 14
// 164.847 us; speedup vs baseline: 1.0834x; 1.0428x over previous
//
#include <hip/hip_runtime.h>
#include <stdint.h>

// ---------- types ----------
typedef __attribute__((ext_vector_type(8))) short s8v;   // 8 bf16 (4 VGPRs)
typedef __attribute__((ext_vector_type(4))) float f4v;   // MFMA accumulator

// ---------- helpers ----------
__device__ __forceinline__ unsigned short f2bf(float f) {
  unsigned u = __float_as_uint(f);
  u = u + 0x7FFFu + ((u >> 16) & 1u);   // RNE
  return (unsigned short)(u >> 16);
}
// monotone float->uint map: order(enc(a)) == order(a); 0 is below enc of any real float.
__device__ __forceinline__ unsigned encf(float f) {
  unsigned i = __float_as_uint(f);
  return (i & 0x80000000u) ? ~i : (i | 0x80000000u);
}
__device__ __forceinline__ float decf(unsigned u) {
  unsigned i = (u & 0x80000000u) ? (u & 0x7FFFFFFFu) : ~u;
  return __uint_as_float(i);
}
__device__ __forceinline__ void gload_lds16(const unsigned short* g, unsigned short* l) {
  __builtin_amdgcn_global_load_lds((const __attribute__((address_space(1))) void*)g,
                                   (__attribute__((address_space(3))) void*)l, 16, 0, 0);
}

// ---------- fused: q,a fp32->bf16; U -> Ut bf16 transposed; zero rmax/cmax + out ----------
__global__ void convert_kernel(const float4* __restrict__ q, const float4* __restrict__ a,
                               const float* __restrict__ U,
                               ushort4* __restrict__ qb, ushort4* __restrict__ ab,
                               unsigned short* __restrict__ Ut,
                               unsigned* __restrict__ rcmax, float* __restrict__ out) {
  const int bx = blockIdx.x;
  if (bx < 8192) {
    const int i = bx * 256 + threadIdx.x;
    float4 v = q[i];
    qb[i] = make_ushort4(f2bf(v.x), f2bf(v.y), f2bf(v.z), f2bf(v.w));
    float4 w = a[i];
    ab[i] = make_ushort4(f2bf(w.x), f2bf(w.y), f2bf(w.z), f2bf(w.w));
  } else if (bx < 8256) {
    // U transpose: 64 blocks x 256 thr, 4 elements each (tiny: 256 KB read)
    const int idx = (bx - 8192) * 256 + threadIdx.x;   // 0..16383
    const int n  = idx >> 6;
    const int k4 = (idx & 63) * 4;
    ushort4 o;
    o.x = f2bf(U[(k4 + 0) * 256 + n]);
    o.y = f2bf(U[(k4 + 1) * 256 + n]);
    o.z = f2bf(U[(k4 + 2) * 256 + n]);
    o.w = f2bf(U[(k4 + 3) * 256 + n]);
    *(ushort4*)&Ut[n * 256 + k4] = o;
  } else if (bx < 8320) {
    // zero rmax+cmax (64K uints): 64 blocks x 256 thr x 4
    const int idx = (bx - 8256) * 256 + threadIdx.x;   // 0..16383
    *(uint4*)&rcmax[idx * 4] = make_uint4(0u, 0u, 0u, 0u);
  } else {
    // zero out (8192 floats): 32 blocks (stream-ordered before wsum's atomics)
    out[(bx - 8320) * 256 + threadIdx.x] = 0.f;
  }
}

// ---------- fused qU-GEMM + S-max: one block per (batch, 128-row slab) ----------
// 512 threads = 8 waves = 2/SIMD (R13's 256-thr version ran 1 wave/SIMD at
// occupancy 10.6% — all latencies exposed; doubling waves is this round's fix).
// Phase 1 (single pass): qU_tile[128][256] = qb_tile[128x256] @ Ut[256x256],
//   wave grid 2x4 (64x64 tiles), staged K=64 slices (A 16 KB + B 32 KB in Bs2);
//   result -> qUs LDS, XOR-swizzled row-major (16B chunk c at c ^ (row&7)).
// Phase 2: loop 16 a-tiles; stage 128x256 a-tile (64 KB, 8 issues) via
//   global_load_lds; wave tile 64x32 (acc[4][2]); rows: per-lane running max ->
//   plain store (block owns rows); cols: LDS atomicMax -> one global pass.
// Grid (b, tm): linear%8 == b%8 pins each batch to one XCD L2.
// Dynamic LDS 139776 B -> 1 block/CU; __launch_bounds__(512,2) = 256 regs/wave
// (same cap as R13's clean codegen; WRITE_SIZE ~2 MB confirmed no spill).
__global__ __launch_bounds__(512, 2)
void fused_qu_smax(const unsigned short* __restrict__ qb,
                   const unsigned short* __restrict__ Ut,
                   const unsigned short* __restrict__ ab,
                   unsigned* __restrict__ rowmax,
                   unsigned* __restrict__ colmax) {
  extern __shared__ char smem[];
  unsigned short* qUs    = (unsigned short*)smem;             // 64 KB: qU tile
  unsigned short* Bs2    = (unsigned short*)(smem + 65536);   // 64 KB: staging
  unsigned*       colLds = (unsigned*)(smem + 131072);        // 8 KB
  unsigned*       rowLds = (unsigned*)(smem + 139264);        // 512 B

  const int tid = threadIdx.x;
  const int b = blockIdx.x, tm = blockIdx.y;

  const int lane = tid & 63;
  const int m16  = lane & 15;
  const int quad = lane >> 4;
  const int wave = tid >> 6;          // 0..7
  const int wm   = wave >> 2;         // 0..1 (row half)
  const int wn   = wave & 3;          // 0..3
  const int srow = tid >> 3;          // staging row (64/issue)
  const int scol = (((tid & 7) ^ (srow & 7))) * 8;   // swizzled source chunk

  #pragma unroll
  for (int i = 0; i < 4; ++i) colLds[i * 512 + tid] = 0u;
  if (tid < 128) rowLds[tid] = 0u;

  // ================= phase 1: qU tile -> LDS (single pass) =================
  const unsigned short* Aq = qb + ((long)b * 2048 + tm * 128) * 256;
  unsigned short* S1 = Bs2;            // 16 KB: A 128x64
  unsigned short* S2 = Bs2 + 8192;     // 32 KB: B 256x64
  {
    f4v acc[4][4] = {};
    for (int kt = 0; kt < 4; ++kt) {
      const int k0 = kt * 64;
      __syncthreads();                 // staging region free
      #pragma unroll
      for (int i = 0; i < 2; ++i)
        gload_lds16(Aq + (long)(i * 64 + srow) * 256 + k0 + scol, &S1[i * 4096 + tid * 8]);
      #pragma unroll
      for (int i = 0; i < 4; ++i)
        gload_lds16(Ut + (long)(i * 64 + srow) * 256 + k0 + scol, &S2[i * 4096 + tid * 8]);
      __syncthreads();                 // staging complete
      #pragma unroll
      for (int kk = 0; kk < 2; ++kk) {
        const int cs = ((kk * 4 + quad) ^ (m16 & 7)) * 8;
        s8v af[4], bfv[4];
        #pragma unroll
        for (int i = 0; i < 4; ++i)
          af[i] = *(const s8v*)&S1[(wm * 64 + i * 16 + m16) * 64 + cs];
        #pragma unroll
        for (int j = 0; j < 4; ++j)
          bfv[j] = *(const s8v*)&S2[(wn * 64 + j * 16 + m16) * 64 + cs];
        #pragma unroll
        for (int i = 0; i < 4; ++i)
          #pragma unroll
          for (int j = 0; j < 4; ++j)
            acc[i][j] = __builtin_amdgcn_mfma_f32_16x16x32_bf16(af[i], bfv[j], acc[i][j], 0, 0, 0);
      }
    }
    // write acc -> qUs (row-major 256 cols, swizzled 16B chunks)
    // C/D layout: col = lane&15, row = quad*4 + reg (verified mapping)
    #pragma unroll
    for (int i = 0; i < 4; ++i)
      #pragma unroll
      for (int r = 0; r < 4; ++r) {
        const int lr = wm * 64 + i * 16 + quad * 4 + r;
        #pragma unroll
        for (int j = 0; j < 4; ++j) {
          const int col = wn * 64 + j * 16 + m16;
          const int ch = (col >> 3) ^ (lr & 7);
          qUs[lr * 256 + ch * 8 + (col & 7)] = f2bf(acc[i][j][r]);
        }
      }
  }
  __syncthreads();   // qUs complete; Bs2 free for phase 2

  // ================= phase 2: 16 a-tiles vs resident qU =================
  const unsigned short* Ab_ = ab + (long)b * 2048 * 256;
  float rmx[4][4];
  #pragma unroll
  for (int i = 0; i < 4; ++i)
    #pragma unroll
    for (int r = 0; r < 4; ++r) rmx[i][r] = -3.4e38f;

  #pragma unroll 1
  for (int tb = 0; tb < 16; ++tb) {
    // stage full 128x256 a-tile (64 KB), swizzled; 8 issues of 8 KB
    #pragma unroll
    for (int e = 0; e < 8; ++e) {
      const int u = e * 512 + tid;          // 16B unit: row = u>>5, chunk = u&31
      const int row = u >> 5;
      const int chs = (u & 31) ^ (row & 7);
      gload_lds16(Ab_ + (long)(tb * 128 + row) * 256 + chs * 8, &Bs2[u * 8]);
    }
    __syncthreads();                        // staging complete
    f4v acc[4][2] = {};
    #pragma unroll
    for (int kq = 0; kq < 8; ++kq) {
      const int cs = ((kq * 4 + quad) ^ (m16 & 7)) * 8;
      s8v af[4], bfv[2];
      #pragma unroll
      for (int i = 0; i < 4; ++i)
        af[i] = *(const s8v*)&qUs[(wm * 64 + i * 16 + m16) * 256 + cs];
      #pragma unroll
      for (int j = 0; j < 2; ++j)
        bfv[j] = *(const s8v*)&Bs2[(wn * 32 + j * 16 + m16) * 256 + cs];
      #pragma unroll
      for (int i = 0; i < 4; ++i)
        #pragma unroll
        for (int j = 0; j < 2; ++j)
          acc[i][j] = __builtin_amdgcn_mfma_f32_16x16x32_bf16(af[i], bfv[j], acc[i][j], 0, 0, 0);
    }
    // per-tile reductions: rows -> running per-lane max; cols -> LDS atomicMax
    #pragma unroll
    for (int i = 0; i < 4; ++i)
      #pragma unroll
      for (int r = 0; r < 4; ++r)
        rmx[i][r] = fmaxf(rmx[i][r], fmaxf(acc[i][0][r], acc[i][1][r]));
    #pragma unroll
    for (int j = 0; j < 2; ++j) {
      float v = -3.4e38f;
      #pragma unroll
      for (int i = 0; i < 4; ++i)
        #pragma unroll
        for (int r = 0; r < 4; ++r) v = fmaxf(v, acc[i][j][r]);
      v = fmaxf(v, __shfl_xor(v, 16));
      v = fmaxf(v, __shfl_xor(v, 32));
      if (quad == 0) atomicMax(&colLds[tb * 128 + wn * 32 + j * 16 + m16], encf(v));
    }
    __syncthreads();                        // compute done -> Bs2 restage-safe
  }

  // ---- final row maxes: shuffle over m16, combine wn-waves via LDS, store ----
  #pragma unroll
  for (int i = 0; i < 4; ++i)
    #pragma unroll
    for (int r = 0; r < 4; ++r) {
      float v = rmx[i][r];
      #pragma unroll
      for (int d2 = 1; d2 < 16; d2 <<= 1) v = fmaxf(v, __shfl_xor(v, d2));
      if (m16 == 0) atomicMax(&rowLds[wm * 64 + i * 16 + quad * 4 + r], encf(v));
    }
  __syncthreads();
  if (tid < 128)
    rowmax[(long)b * 2048 + tm * 128 + tid] = rowLds[tid];   // plain store (block owns rows)
  // ---- col maxes: one global atomic pass ----
  #pragma unroll
  for (int i = 0; i < 4; ++i)
    atomicMax(&colmax[(long)b * 2048 + i * 512 + tid], colLds[i * 512 + tid]);
}

// ---------- fused softmax + weighted sum (bf16 inputs, 16B/lane loads) ----------
__global__ void wsum_kernel(const uint4* __restrict__ qb, const uint4* __restrict__ ab,
                            const unsigned* __restrict__ rowmax, const unsigned* __restrict__ colmax,
                            float* __restrict__ out) {
  const int tid = threadIdx.x;
  const int chunk = blockIdx.x;
  const int b = blockIdx.y;
  const int z = blockIdx.z;
  const unsigned* e = z ? colmax : rowmax;
  const uint4* src = z ? ab : qb;

  __shared__ float sm[4];
  __shared__ float ss[4];
  __shared__ float wLds[128];
  __shared__ float red[256 * 8];   // 8 KB

  float x[8];
  float m = -3.4e38f;
  #pragma unroll
  for (int j = 0; j < 8; ++j) {
    x[j] = tanhf(decf(e[b * 2048 + j * 256 + tid]));
    m = fmaxf(m, x[j]);
  }
  #pragma unroll
  for (int d2 = 1; d2 < 64; d2 <<= 1) m = fmaxf(m, __shfl_xor(m, d2));
  if ((tid & 63) == 0) sm[tid >> 6] = m;
  __syncthreads();
  m = fmaxf(fmaxf(sm[0], sm[1]), fmaxf(sm[2], sm[3]));
  float s = 0.f;
  #pragma unroll
  for (int j = 0; j < 8; ++j) s += expf(x[j] - m);
  #pragma unroll
  for (int d2 = 1; d2 < 64; d2 <<= 1) s += __shfl_xor(s, d2);
  if ((tid & 63) == 0) ss[tid >> 6] = s;
  __syncthreads();
  const float inv = 1.f / (ss[0] + ss[1] + ss[2] + ss[3]);

  if (tid < 128) {
    float xv = tanhf(decf(e[b * 2048 + chunk * 128 + tid]));
    wLds[tid] = expf(xv - m) * inv;
  }
  __syncthreads();

  const int dg = tid & 31;
  const int rg = tid >> 5;       // 0..7, rows stride 8
  float acc[8] = {};
  const long rowbase = (long)b * 2048 + chunk * 128;
  for (int t = rg; t < 128; t += 8) {
    const float wgt = wLds[t];
    uint4 v = src[(rowbase + t) * 32 + dg];
    acc[0] += wgt * __uint_as_float(v.x << 16);
    acc[1] += wgt * __uint_as_float(v.x & 0xFFFF0000u);
    acc[2] += wgt * __uint_as_float(v.y << 16);
    acc[3] += wgt * __uint_as_float(v.y & 0xFFFF0000u);
    acc[4] += wgt * __uint_as_float(v.z << 16);
    acc[5] += wgt * __uint_as_float(v.z & 0xFFFF0000u);
    acc[6] += wgt * __uint_as_float(v.w << 16);
    acc[7] += wgt * __uint_as_float(v.w & 0xFFFF0000u);
  }
  #pragma unroll
  for (int k = 0; k < 8; ++k) red[tid * 8 + k] = acc[k];
  __syncthreads();
  if (tid < 32) {
    #pragma unroll
    for (int k = 0; k < 8; ++k) {
      float v = 0.f;
      #pragma unroll
      for (int g = 0; g < 8; ++g) v += red[((g << 5) | tid) * 8 + k];
      atomicAdd(&out[z * 4096 + b * 256 + tid * 8 + k], v);
    }
  }
}

// ---------- launch ----------
extern "C" void kernel_launch(void* const* d_in, const int* in_sizes, int n_in,
                              void* d_out, int out_size, void* d_ws, size_t ws_size,
                              hipStream_t stream) {
  const float* q = (const float*)d_in[0];
  const float* a = (const float*)d_in[1];
  const float* U = (const float*)d_in[2];
  float* out = (float*)d_out;

  char* w = (char*)d_ws;
  unsigned short* qb = (unsigned short*)w;                       // 16 MB
  unsigned short* ab = (unsigned short*)(w + (16ull << 20));     // 16 MB
  unsigned short* Ut = (unsigned short*)(w + (32ull << 20));     // 128 KB
  unsigned* rmax = (unsigned*)(w + (32ull << 20) + (128ull << 10));
  unsigned* cmax = rmax + 32768;

  // allow 139776 B dynamic LDS for the fused kernel (host-side, idempotent)
  constexpr int SMEM = 139776;
  hipFuncSetAttribute((const void*)fused_qu_smax,
                      hipFuncAttributeMaxDynamicSharedMemorySize, SMEM);

  // fused q/a bf16-cast + U transpose + rmax/cmax zero + out zero
  convert_kernel<<<8352, 256, 0, stream>>>((const float4*)q, (const float4*)a, U,
                                           (ushort4*)qb, (ushort4*)ab, Ut, rmax, out);

  // qU tile in LDS + S row/col maxes; grid (b, tm) -> XCD == b%8; 8 waves/block
  fused_qu_smax<<<dim3(16, 16), 512, SMEM, stream>>>(qb, Ut, ab, rmax, cmax);

  // fused softmax + weighted pooling (bf16, 16B/lane)
  wsum_kernel<<<dim3(16, 16, 2), 256, 0, stream>>>((const uint4*)qb, (const uint4*)ab,
                                                   rmax, cmax, out);
}